// Round 8
// baseline (7875.913 us; speedup 1.0000x reference)
//
#include <hip/hip_runtime.h>
#include <math.h>

#define Bsz 32
#define Hd  512
#define SEQ 128
#define G4H 2048
#define BH  16384   // Bsz*Hd
#define BARSTRIDE 32

typedef __attribute__((ext_vector_type(8))) short bf16x8;
typedef __attribute__((ext_vector_type(4))) float f32x4;
typedef __attribute__((ext_vector_type(4))) unsigned short us4;

__device__ __forceinline__ void gload16(const void* g, void* l) {
  __builtin_amdgcn_global_load_lds(
      (const __attribute__((address_space(1))) unsigned int*)g,
      (__attribute__((address_space(3))) unsigned int*)l, 16, 0, 0);
}

// ---------------- weight pre-pack v2: per-cell wave panels ----------------
// out[n][ ((c*16+kk)*8+ks)*4 + g ] = W[g*512+n][ks*64 + c*16 + kk]
__global__ __launch_bounds__(256) void pack_w2_k(const float* __restrict__ W,
                                                 float* __restrict__ out) {
  __shared__ float Wl[4][512];
  const int n = blockIdx.x, tid = threadIdx.x;
  #pragma unroll
  for (int g = 0; g < 4; ++g) {
    Wl[g][tid]       = W[(size_t)(g * Hd + n) * Hd + tid];
    Wl[g][tid + 256] = W[(size_t)(g * Hd + n) * Hd + tid + 256];
  }
  __syncthreads();
  #pragma unroll
  for (int j = 0; j < 8; ++j) {
    int i = tid * 8 + j;
    int g = i & 3, ks = (i >> 2) & 7, kk = (i >> 5) & 15, c = i >> 9;
    out[(size_t)n * 2048 + i] = Wl[g][ks * 64 + c * 16 + kk];
  }
}

__global__ __launch_bounds__(256) void bias_sum_k(const float* __restrict__ a,
                                                  const float* __restrict__ b,
                                                  float* __restrict__ out) {
  int i = blockIdx.x * 256 + threadIdx.x;
  if (i < G4H) out[i] = a[i] + b[i];
}

__global__ __launch_bounds__(256) void embed_k(const int* __restrict__ idx,
                                               const float* __restrict__ emb,
                                               float* __restrict__ out) {
  int t = blockIdx.x * 256 + threadIdx.x;
  int m = t >> 6, e4 = (t & 63) << 2;
  *(float4*)&out[(size_t)m * 256 + e4] =
      *(const float4*)&emb[(size_t)idx[m] * 256 + e4];
}

// ---------------- fp32 -> bf16 hi/lo split ----------------
__global__ __launch_bounds__(256) void split_k(const float* __restrict__ X,
                                               unsigned short* __restrict__ hi,
                                               unsigned short* __restrict__ lo) {
  int i = (blockIdx.x * 256 + threadIdx.x) << 2;
  float4 x = *(const float4*)&X[i];
  const float* xp = (const float*)&x;
  us4 h, l;
  #pragma unroll
  for (int e = 0; e < 4; ++e) {
    float v = xp[e];
    unsigned int u = __float_as_uint(v);
    unsigned int hr = (u + 0x7fffu + ((u >> 16) & 1u)) & 0xffff0000u;
    h[e] = (unsigned short)(hr >> 16);
    float rem = v - __uint_as_float(hr);
    unsigned int u2 = __float_as_uint(rem);
    l[e] = (unsigned short)((u2 + 0x7fffu + ((u2 >> 16) & 1u)) >> 16);
  }
  *(us4*)&hi[i] = h;
  *(us4*)&lo[i] = l;
}

// ---------------- fp32 NT GEMM (input gates + fallback) ----------------
__global__ __launch_bounds__(256, 2)
void gemm_nt_k(const float* __restrict__ A, const float* __restrict__ Wt,
               const float* __restrict__ bias, float* __restrict__ C,
               int K, int ldc)
{
  __shared__ float As[32 * 68];
  __shared__ float Ws[32 * 68];
  const int tid = threadIdx.x;
  const int m0 = blockIdx.y << 6, n0 = blockIdx.x << 6;
  const int tn = tid & 15, tm = tid >> 4;
  const int lr = tid >> 2, lk = (tid & 3) << 3;
  float acc[4][4] = {};
  for (int kt = 0; kt < K; kt += 32) {
    #pragma unroll
    for (int i = 0; i < 2; ++i) {
      float4 a = *(const float4*)&A[(size_t)(m0 + lr) * K + kt + lk + (i << 2)];
      float4 w = *(const float4*)&Wt[(size_t)(n0 + lr) * K + kt + lk + (i << 2)];
      const float* ap = (const float*)&a;
      const float* wp = (const float*)&w;
      #pragma unroll
      for (int d = 0; d < 4; ++d) {
        As[(lk + (i << 2) + d) * 68 + lr] = ap[d];
        Ws[(lk + (i << 2) + d) * 68 + lr] = wp[d];
      }
    }
    __syncthreads();
    #pragma unroll 8
    for (int kk = 0; kk < 32; ++kk) {
      float4 av = *(const float4*)&As[kk * 68 + (tm << 2)];
      float4 wv = *(const float4*)&Ws[kk * 68 + (tn << 2)];
      const float* ap = (const float*)&av;
      const float* wp = (const float*)&wv;
      #pragma unroll
      for (int i = 0; i < 4; ++i)
        #pragma unroll
        for (int j = 0; j < 4; ++j)
          acc[i][j] += ap[i] * wp[j];
    }
    __syncthreads();
  }
  #pragma unroll
  for (int i = 0; i < 4; ++i) {
    float4 o;
    float* op = (float*)&o;
    #pragma unroll
    for (int j = 0; j < 4; ++j) op[j] = acc[i][j] + bias[n0 + (tn << 2) + j];
    *(float4*)&C[(size_t)(m0 + (tm << 2) + i) * ldc + n0 + (tn << 2)] = o;
  }
}

// ---------------- bf16 MFMA 3-term split projection ----------------
__global__ __launch_bounds__(256)
void gemm_bf16_split_k(const unsigned short* __restrict__ Ahi,
                       const unsigned short* __restrict__ Alo,
                       const unsigned short* __restrict__ Bhi,
                       const unsigned short* __restrict__ Blo,
                       const float* __restrict__ bias,
                       float* __restrict__ C)
{
  __shared__ unsigned short As[4096];   // [128][32]
  __shared__ unsigned short Bs[4096];   // [128][32]
  const int tid = threadIdx.x;
  const int m0 = blockIdx.x << 7, n0 = blockIdx.y << 7;
  const int lane = tid & 63, wave = tid >> 6;
  const int wr = wave >> 1, wc = wave & 1;
  const int srow = wave * 32 + (lane >> 2);
  const int sk = (lane & 3) << 3;
  const int ldse = wave * 1024 + lane * 8;
  const int fr = lane & 15, fk = (lane >> 4) << 3;

  f32x4 acc[4][4];
  #pragma unroll
  for (int a = 0; a < 4; ++a)
    #pragma unroll
    for (int b = 0; b < 4; ++b) acc[a][b] = (f32x4){0.f, 0.f, 0.f, 0.f};

  #pragma unroll 1
  for (int seg = 0; seg < 3; ++seg) {
    const unsigned short* Ab = (seg == 2) ? Alo : Ahi;
    const unsigned short* Bb = (seg == 1) ? Blo : Bhi;
    #pragma unroll 1
    for (int kt = 0; kt < 512; kt += 32) {
      gload16(Ab + (size_t)(m0 + srow) * 512 + kt + sk, &As[ldse]);
      gload16(Ab + (size_t)(m0 + srow + 16) * 512 + kt + sk, &As[ldse + 512]);
      gload16(Bb + (size_t)(n0 + srow) * 512 + kt + sk, &Bs[ldse]);
      gload16(Bb + (size_t)(n0 + srow + 16) * 512 + kt + sk, &Bs[ldse + 512]);
      __syncthreads();
      bf16x8 af[4], bf[4];
      #pragma unroll
      for (int mf = 0; mf < 4; ++mf)
        af[mf] = *(const bf16x8*)&As[(wr * 64 + mf * 16 + fr) * 32 + fk];
      #pragma unroll
      for (int nf = 0; nf < 4; ++nf)
        bf[nf] = *(const bf16x8*)&Bs[(wc * 64 + nf * 16 + fr) * 32 + fk];
      #pragma unroll
      for (int mf = 0; mf < 4; ++mf)
        #pragma unroll
        for (int nf = 0; nf < 4; ++nf)
          acc[mf][nf] = __builtin_amdgcn_mfma_f32_16x16x32_bf16(af[mf], bf[nf],
                                                                acc[mf][nf], 0, 0, 0);
      __syncthreads();
    }
  }

  const int rgrp = (lane >> 4) << 2;
  #pragma unroll
  for (int nf = 0; nf < 4; ++nf) {
    int n = n0 + wc * 64 + nf * 16 + fr;
    float bn = bias[n];
    #pragma unroll
    for (int mf = 0; mf < 4; ++mf) {
      #pragma unroll
      for (int r = 0; r < 4; ++r) {
        int m = m0 + wr * 64 + mf * 16 + rgrp + r;
        C[(size_t)m * 32000 + n] = acc[mf][nf][r] + bn;
      }
    }
  }
}

// ---------------- per-wave flag sync (512 wave flags, in-wave poll) ----------------
__device__ __forceinline__ void pollw(const int* arr, int target) {
  const int lane = threadIdx.x & 63;
  const int* p = &arr[(lane << 3) * BARSTRIDE];
  for (;;) {
    int m = 0x7fffffff;
    #pragma unroll
    for (int j = 0; j < 8; ++j)
      m = min(m, __hip_atomic_load(&p[j * BARSTRIDE], __ATOMIC_RELAXED,
                                   __HIP_MEMORY_SCOPE_AGENT));
    if (__all(m >= target)) break;
    __builtin_amdgcn_s_sleep(1);
  }
}

// one 512-k matmul: wave lanes (bg,ks), per-lane 4 batch x 64 k, acc[gate][bi]
#define MM512(WP, HP)                                                          \
  {                                                                            \
    _Pragma("unroll")                                                          \
    for (int c = 0; c < 4; ++c) {                                              \
      float hr[4][16];                                                         \
      _Pragma("unroll")                                                        \
      for (int bi = 0; bi < 4; ++bi) {                                         \
        _Pragma("unroll")                                                      \
        for (int q = 0; q < 4; ++q) {                                          \
          float4 t4 = *(const float4*)&(HP)[(bg * 4 + bi) * Hd + ks * 64 + c * 16 + q * 4]; \
          hr[bi][q * 4 + 0] = t4.x; hr[bi][q * 4 + 1] = t4.y;                  \
          hr[bi][q * 4 + 2] = t4.z; hr[bi][q * 4 + 3] = t4.w;                  \
        }                                                                      \
      }                                                                        \
      _Pragma("unroll")                                                        \
      for (int kk = 0; kk < 16; ++kk) {                                        \
        float4 w4 = *(const float4*)&(WP)[((c * 16 + kk) * 8 + ks) * 4];       \
        _Pragma("unroll")                                                      \
        for (int bi = 0; bi < 4; ++bi) {                                       \
          acc[0][bi] += w4.x * hr[bi][kk];                                     \
          acc[1][bi] += w4.y * hr[bi][kk];                                     \
          acc[2][bi] += w4.z * hr[bi][kk];                                     \
          acc[3][bi] += w4.w * hr[bi][kk];                                     \
        }                                                                      \
      }                                                                        \
    }                                                                          \
  }

#define KREDUCE()                                                              \
  _Pragma("unroll")                                                            \
  for (int g = 0; g < 4; ++g) {                                                \
    _Pragma("unroll")                                                          \
    for (int bi = 0; bi < 4; ++bi) {                                           \
      float v = acc[g][bi];                                                    \
      v += __shfl_xor(v, 8, 64);                                               \
      v += __shfl_xor(v, 16, 64);                                              \
      v += __shfl_xor(v, 32, 64);                                              \
      acc[g][bi] = v;                                                          \
    }                                                                          \
  }

// ---------------- persistent LSTM: wave-decoupled layers, no block barriers ----------------
// Wave 0/1: layer0 cell blk*2+{0,1}; wave 2/3: layer1 cell blk*2+{0,1}.
// Per-wave flags (512 each); in-wave shuffle reduce; sc1 write-through h; write-once slots.
__global__ __launch_bounds__(256, 1)
void lstm_seq_k(const float* __restrict__ w0p,  // packed Whh0  [512 cells][2048]
                const float* __restrict__ w1ap, // packed Wih1
                const float* __restrict__ w1bp, // packed Whh1
                const float* __restrict__ x0pre,// [B*SEQ][2048] input gates (+biases)
                const float* __restrict__ bias1,// [2048] bih1+bhh1
                float* __restrict__ h0steps, float* __restrict__ h1steps,
                const float* __restrict__ h0init, const float* __restrict__ h1init,
                const float* __restrict__ c0init, const float* __restrict__ c1init,
                float* __restrict__ c0fin, float* __restrict__ c1fin,
                float* __restrict__ dec_out,    // [B][SEQ][Hd] or nullptr
                int* __restrict__ flag0, int* __restrict__ flag1)
{
  __shared__ float wlds[3][2][2048];

  const int blk = blockIdx.x, tid = threadIdx.x;
  const int wave = tid >> 6, lane = tid & 63;
  const int bg = lane & 7, ks = lane >> 3;
  const int cl = wave & 1;
  const int n = (blk << 1) + cl;
  const bool isL0 = (wave < 2);

  // stage packed panels for this block's two cells (3 matrices)
  for (int i = tid * 4; i < 4096; i += 1024) {
    *(float4*)&wlds[0][0][i] = *(const float4*)&w0p[((size_t)blk << 12) + i];
    *(float4*)&wlds[1][0][i] = *(const float4*)&w1ap[((size_t)blk << 12) + i];
    *(float4*)&wlds[2][0][i] = *(const float4*)&w1bp[((size_t)blk << 12) + i];
  }

  // loop-invariant per-lane state (replicated across ks lanes)
  float creg[4];
  {
    const float* ci = isL0 ? c0init : c1init;
    #pragma unroll
    for (int bi = 0; bi < 4; ++bi) creg[bi] = ci[(bg * 4 + bi) * Hd + n];
  }
  float bv4[4];
  #pragma unroll
  for (int g = 0; g < 4; ++g) bv4[g] = bias1[g * Hd + n];
  __syncthreads();

  if (isL0) {
    const float* wA = &wlds[0][cl][0];
    #pragma unroll 1
    for (int u = 0; u < SEQ; ++u) {
      // x prefetch (static addresses; overlaps the poll)
      float xv[4][4];
      #pragma unroll
      for (int g = 0; g < 4; ++g)
        #pragma unroll
        for (int bi = 0; bi < 4; ++bi)
          xv[g][bi] = x0pre[(size_t)((bg * 4 + bi) * SEQ + u) * G4H + g * Hd + n];
      if (u > 0) pollw(flag0, u);                 // h0(u-1) ready
      const float* hp = (u == 0) ? h0init : h0steps + (size_t)(u - 1) * BH;
      float acc[4][4] = {};
      MM512(wA, hp);
      KREDUCE();
      float hn4[4];
      #pragma unroll
      for (int bi = 0; bi < 4; ++bi) {
        float i_ = 1.f / (1.f + expf(-(acc[0][bi] + xv[0][bi])));
        float f_ = 1.f / (1.f + expf(-(acc[1][bi] + xv[1][bi])));
        float g_ = tanhf(acc[2][bi] + xv[2][bi]);
        float o_ = 1.f / (1.f + expf(-(acc[3][bi] + xv[3][bi])));
        float cn = f_ * creg[bi] + i_ * g_;
        hn4[bi] = o_ * tanhf(cn);
        creg[bi] = cn;
      }
      if (ks == 0) {
        #pragma unroll
        for (int bi = 0; bi < 4; ++bi)
          __hip_atomic_store(&h0steps[(size_t)u * BH + (bg * 4 + bi) * Hd + n],
                             hn4[bi], __ATOMIC_RELAXED, __HIP_MEMORY_SCOPE_AGENT);
      }
      if (lane == 0) {
        asm volatile("s_waitcnt vmcnt(0)" ::: "memory");
        __hip_atomic_store(&flag0[n * BARSTRIDE], u + 1,
                           __ATOMIC_RELAXED, __HIP_MEMORY_SCOPE_AGENT);
      }
    }
  } else {
    const float* wA = &wlds[1][cl][0];   // Wih1 (x hA = h0(u-1))
    const float* wB = &wlds[2][cl][0];   // Whh1 (x hB = h1(u-2))
    #pragma unroll 1
    for (int u = 1; u <= SEQ; ++u) {
      // B-part first: h1(u-2) is 1+ epochs old -> wait normally satisfied
      if (u >= 2) pollw(flag1, u - 1);
      const float* hbp = (u == 1) ? h1init : h1steps + (size_t)(u - 2) * BH;
      float acc[4][4] = {};
      MM512(wB, hbp);
      pollw(flag0, u);                             // h0(u-1) ready
      const float* hap = h0steps + (size_t)(u - 1) * BH;
      MM512(wA, hap);
      KREDUCE();
      const int t = u - 1;
      float hn4[4];
      #pragma unroll
      for (int bi = 0; bi < 4; ++bi) {
        float i_ = 1.f / (1.f + expf(-(acc[0][bi] + bv4[0])));
        float f_ = 1.f / (1.f + expf(-(acc[1][bi] + bv4[1])));
        float g_ = tanhf(acc[2][bi] + bv4[2]);
        float o_ = 1.f / (1.f + expf(-(acc[3][bi] + bv4[3])));
        float cn = f_ * creg[bi] + i_ * g_;
        hn4[bi] = o_ * tanhf(cn);
        creg[bi] = cn;
      }
      if (ks == 0) {
        #pragma unroll
        for (int bi = 0; bi < 4; ++bi) {
          int b = bg * 4 + bi;
          __hip_atomic_store(&h1steps[(size_t)t * BH + b * Hd + n],
                             hn4[bi], __ATOMIC_RELAXED, __HIP_MEMORY_SCOPE_AGENT);
          if (dec_out) dec_out[((size_t)b * SEQ + t) * Hd + n] = hn4[bi];
        }
      }
      if (lane == 0) {
        asm volatile("s_waitcnt vmcnt(0)" ::: "memory");
        __hip_atomic_store(&flag1[n * BARSTRIDE], u,
                           __ATOMIC_RELAXED, __HIP_MEMORY_SCOPE_AGENT);
      }
    }
  }

  // final c handoff
  if (ks == 0) {
    float* cf = isL0 ? c0fin : c1fin;
    #pragma unroll
    for (int bi = 0; bi < 4; ++bi) cf[(bg * 4 + bi) * Hd + n] = creg[bi];
  }
}

// ---------------- host ----------------
extern "C" void kernel_launch(void* const* d_in, const int* in_sizes, int n_in,
                              void* d_out, int out_size, void* d_ws, size_t ws_size,
                              hipStream_t stream) {
  const int*   src  = (const int*)d_in[0];
  const int*   tgt  = (const int*)d_in[1];
  const float* emb  = (const float*)d_in[2];
  const float* Wout = (const float*)d_in[3];
  const float* bout = (const float*)d_in[4];
  const float* eWih0 = (const float*)d_in[5];
  const float* eWhh0 = (const float*)d_in[6];
  const float* ebih0 = (const float*)d_in[7];
  const float* ebhh0 = (const float*)d_in[8];
  const float* eWih1 = (const float*)d_in[9];
  const float* eWhh1 = (const float*)d_in[10];
  const float* ebih1 = (const float*)d_in[11];
  const float* ebhh1 = (const float*)d_in[12];
  const float* dWih0 = (const float*)d_in[13];
  const float* dWhh0 = (const float*)d_in[14];
  const float* dbih0 = (const float*)d_in[15];
  const float* dbhh0 = (const float*)d_in[16];
  const float* dWih1 = (const float*)d_in[17];
  const float* dWhh1 = (const float*)d_in[18];
  const float* dbih1 = (const float*)d_in[19];
  const float* dbhh1 = (const float*)d_in[20];

  float* ws = (float*)d_ws;
  char*  wsb = (char*)d_ws;
  // float offsets
  const size_t OFF_EMB  = 0;          // dead after input gemms
  const size_t OFF_X0   = 1048576;
  const size_t OFF_W0E  = 9437184;
  const size_t OFF_W1AE = 10485760;
  const size_t OFF_W1BE = 11534336;
  const size_t OFF_W0D  = 12582912;
  const size_t OFF_W1AD = 13631488;
  const size_t OFF_W1BD = 14680064;
  const size_t OFF_BS0E = 15728640;
  const size_t OFF_B1E  = 15730688;
  const size_t OFF_BS0D = 15732736;
  const size_t OFF_B1D  = 15734784;
  const size_t OFF_H0   = 15736832;   // 128*BH (per-step h0 slots)
  const size_t OFF_H1   = 17833984;   // 128*BH
  const size_t OFF_C0   = 19931136;   // BH (enc-final c0 -> dec init)
  const size_t OFF_C1   = 19947520;   // BH
  const size_t OFF_Z    = 19963904;   // BH zeros
  const size_t OFF_BAR  = 19980288;   // 4 x 16384 ints (e0,e1,d0,d1; 512 waves x 32)
  const size_t OFF_DOUT = 20045824;   // 2,097,152 f -> byte end 88,571,904
  unsigned short* Ahi = (unsigned short*)(wsb + 88571904);   // 4096*512
  unsigned short* Alo = (unsigned short*)(wsb + 92766208);   // 4096*512
  unsigned short* Bhi = (unsigned short*)(wsb + 0);          // 32000*512 (dead low region)
  unsigned short* Blo = (unsigned short*)(wsb + 32768000);
  const bool use_mfma = ws_size >= 96960512ull;

  int* e0 = (int*)(ws + OFF_BAR);
  int* e1 = e0 + 16384;
  int* d0 = e0 + 32768;
  int* d1 = e0 + 49152;

  // pack weights (per-cell wave panels) + bias sums
  pack_w2_k<<<512, 256, 0, stream>>>(eWhh0, ws + OFF_W0E);
  pack_w2_k<<<512, 256, 0, stream>>>(eWih1, ws + OFF_W1AE);
  pack_w2_k<<<512, 256, 0, stream>>>(eWhh1, ws + OFF_W1BE);
  pack_w2_k<<<512, 256, 0, stream>>>(dWhh0, ws + OFF_W0D);
  pack_w2_k<<<512, 256, 0, stream>>>(dWih1, ws + OFF_W1AD);
  pack_w2_k<<<512, 256, 0, stream>>>(dWhh1, ws + OFF_W1BD);
  bias_sum_k<<<8, 256, 0, stream>>>(ebih0, ebhh0, ws + OFF_BS0E);
  bias_sum_k<<<8, 256, 0, stream>>>(ebih1, ebhh1, ws + OFF_B1E);
  bias_sum_k<<<8, 256, 0, stream>>>(dbih0, dbhh0, ws + OFF_BS0D);
  bias_sum_k<<<8, 256, 0, stream>>>(dbih1, dbhh1, ws + OFF_B1D);

  // zero zbuf + all flag arrays every call (graph replay safe)
  hipMemsetAsync(ws + OFF_Z, 0, (size_t)(BH + 65536) * 4, stream);

  // encoder
  embed_k<<<1024, 256, 0, stream>>>(src, emb, ws + OFF_EMB);
  gemm_nt_k<<<dim3(32, 64), 256, 0, stream>>>(ws + OFF_EMB, eWih0, ws + OFF_BS0E,
                                              ws + OFF_X0, 256, 2048);
  lstm_seq_k<<<256, 256, 0, stream>>>(ws + OFF_W0E, ws + OFF_W1AE, ws + OFF_W1BE,
                                      ws + OFF_X0, ws + OFF_B1E,
                                      ws + OFF_H0, ws + OFF_H1,
                                      ws + OFF_Z, ws + OFF_Z,      // h inits (zeros)
                                      ws + OFF_Z, ws + OFF_Z,      // c inits (zeros)
                                      ws + OFF_C0, ws + OFF_C1,    // c finals
                                      nullptr, e0, e1);

  // decoder (inits = encoder finals)
  embed_k<<<1024, 256, 0, stream>>>(tgt, emb, ws + OFF_EMB);
  gemm_nt_k<<<dim3(32, 64), 256, 0, stream>>>(ws + OFF_EMB, dWih0, ws + OFF_BS0D,
                                              ws + OFF_X0, 256, 2048);
  lstm_seq_k<<<256, 256, 0, stream>>>(ws + OFF_W0D, ws + OFF_W1AD, ws + OFF_W1BD,
                                      ws + OFF_X0, ws + OFF_B1D,
                                      ws + OFF_H0, ws + OFF_H1,
                                      ws + OFF_H0 + (size_t)127 * BH,
                                      ws + OFF_H1 + (size_t)127 * BH,
                                      ws + OFF_C0, ws + OFF_C1,
                                      ws + OFF_C0, ws + OFF_C1,
                                      ws + OFF_DOUT, d0, d1);

  // vocab projection
  if (use_mfma) {
    split_k<<<2048, 256, 0, stream>>>(ws + OFF_DOUT, Ahi, Alo);
    split_k<<<16000, 256, 0, stream>>>(Wout, Bhi, Blo);   // overlays dead low region
    gemm_bf16_split_k<<<dim3(32, 250), 256, 0, stream>>>(Ahi, Alo, Bhi, Blo,
                                                         bout, (float*)d_out);
  } else {
    gemm_nt_k<<<dim3(500, 64), 256, 0, stream>>>(ws + OFF_DOUT, Wout, bout,
                                                 (float*)d_out, 512, 32000);
  }
}

// Round 9
// 3163.103 us; speedup vs baseline: 2.4899x; 2.4899x over previous
//
#include <hip/hip_runtime.h>
#include <math.h>

#define Bsz 32
#define Hd  512
#define SEQ 128
#define G4H 2048
#define BH  16384   // Bsz*Hd
#define BARSTRIDE 32

typedef __attribute__((ext_vector_type(8))) short bf16x8;
typedef __attribute__((ext_vector_type(4))) float f32x4;
typedef __attribute__((ext_vector_type(4))) unsigned short us4;

__device__ __forceinline__ void gload16(const void* g, void* l) {
  __builtin_amdgcn_global_load_lds(
      (const __attribute__((address_space(1))) unsigned int*)g,
      (__attribute__((address_space(3))) unsigned int*)l, 16, 0, 0);
}

// ---------------- weight pre-pack (coalesced via LDS) ----------------
__global__ __launch_bounds__(256) void pack_w_k(const float* __restrict__ W,
                                                float* __restrict__ out) {
  __shared__ float Wl[8][512];
  const int blk = blockIdx.x, tid = threadIdx.x;
  #pragma unroll
  for (int r = 0; r < 8; ++r) {
    int j = ((r >> 1) << 9) + (blk << 1) + (r & 1);
    Wl[r][tid] = W[j * Hd + tid];
    Wl[r][tid + 256] = W[j * Hd + tid + 256];
  }
  __syncthreads();
  #pragma unroll
  for (int q = 0; q < 16; ++q) {
    int i = tid * 16 + q;
    int kk = i >> 8, rest = i & 255, ks2 = rest >> 3, jj = rest & 7;
    out[((size_t)blk << 12) + i] = Wl[jj][(ks2 << 4) + kk];
  }
}

__global__ __launch_bounds__(256) void bias_sum_k(const float* __restrict__ a,
                                                  const float* __restrict__ b,
                                                  float* __restrict__ out) {
  int i = blockIdx.x * 256 + threadIdx.x;
  if (i < G4H) out[i] = a[i] + b[i];
}

__global__ __launch_bounds__(256) void embed_k(const int* __restrict__ idx,
                                               const float* __restrict__ emb,
                                               float* __restrict__ out) {
  int t = blockIdx.x * 256 + threadIdx.x;
  int m = t >> 6, e4 = (t & 63) << 2;
  *(float4*)&out[(size_t)m * 256 + e4] =
      *(const float4*)&emb[(size_t)idx[m] * 256 + e4];
}

// ---------------- fp32 -> bf16 hi/lo split ----------------
__global__ __launch_bounds__(256) void split_k(const float* __restrict__ X,
                                               unsigned short* __restrict__ hi,
                                               unsigned short* __restrict__ lo) {
  int i = (blockIdx.x * 256 + threadIdx.x) << 2;
  float4 x = *(const float4*)&X[i];
  const float* xp = (const float*)&x;
  us4 h, l;
  #pragma unroll
  for (int e = 0; e < 4; ++e) {
    float v = xp[e];
    unsigned int u = __float_as_uint(v);
    unsigned int hr = (u + 0x7fffu + ((u >> 16) & 1u)) & 0xffff0000u;
    h[e] = (unsigned short)(hr >> 16);
    float rem = v - __uint_as_float(hr);
    unsigned int u2 = __float_as_uint(rem);
    l[e] = (unsigned short)((u2 + 0x7fffu + ((u2 >> 16) & 1u)) >> 16);
  }
  *(us4*)&hi[i] = h;
  *(us4*)&lo[i] = l;
}

// ---------------- fp32 NT GEMM (input gates + fallback) ----------------
__global__ __launch_bounds__(256, 2)
void gemm_nt_k(const float* __restrict__ A, const float* __restrict__ Wt,
               const float* __restrict__ bias, float* __restrict__ C,
               int K, int ldc)
{
  __shared__ float As[32 * 68];
  __shared__ float Ws[32 * 68];
  const int tid = threadIdx.x;
  const int m0 = blockIdx.y << 6, n0 = blockIdx.x << 6;
  const int tn = tid & 15, tm = tid >> 4;
  const int lr = tid >> 2, lk = (tid & 3) << 3;
  float acc[4][4] = {};
  for (int kt = 0; kt < K; kt += 32) {
    #pragma unroll
    for (int i = 0; i < 2; ++i) {
      float4 a = *(const float4*)&A[(size_t)(m0 + lr) * K + kt + lk + (i << 2)];
      float4 w = *(const float4*)&Wt[(size_t)(n0 + lr) * K + kt + lk + (i << 2)];
      const float* ap = (const float*)&a;
      const float* wp = (const float*)&w;
      #pragma unroll
      for (int d = 0; d < 4; ++d) {
        As[(lk + (i << 2) + d) * 68 + lr] = ap[d];
        Ws[(lk + (i << 2) + d) * 68 + lr] = wp[d];
      }
    }
    __syncthreads();
    #pragma unroll 8
    for (int kk = 0; kk < 32; ++kk) {
      float4 av = *(const float4*)&As[kk * 68 + (tm << 2)];
      float4 wv = *(const float4*)&Ws[kk * 68 + (tn << 2)];
      const float* ap = (const float*)&av;
      const float* wp = (const float*)&wv;
      #pragma unroll
      for (int i = 0; i < 4; ++i)
        #pragma unroll
        for (int j = 0; j < 4; ++j)
          acc[i][j] += ap[i] * wp[j];
    }
    __syncthreads();
  }
  #pragma unroll
  for (int i = 0; i < 4; ++i) {
    float4 o;
    float* op = (float*)&o;
    #pragma unroll
    for (int j = 0; j < 4; ++j) op[j] = acc[i][j] + bias[n0 + (tn << 2) + j];
    *(float4*)&C[(size_t)(m0 + (tm << 2) + i) * ldc + n0 + (tn << 2)] = o;
  }
}

// ---------------- bf16 MFMA 3-term split projection ----------------
__global__ __launch_bounds__(256)
void gemm_bf16_split_k(const unsigned short* __restrict__ Ahi,
                       const unsigned short* __restrict__ Alo,
                       const unsigned short* __restrict__ Bhi,
                       const unsigned short* __restrict__ Blo,
                       const float* __restrict__ bias,
                       float* __restrict__ C)
{
  __shared__ unsigned short As[4096];   // [128][32]
  __shared__ unsigned short Bs[4096];   // [128][32]
  const int tid = threadIdx.x;
  const int m0 = blockIdx.x << 7, n0 = blockIdx.y << 7;
  const int lane = tid & 63, wave = tid >> 6;
  const int wr = wave >> 1, wc = wave & 1;
  const int srow = wave * 32 + (lane >> 2);
  const int sk = (lane & 3) << 3;
  const int ldse = wave * 1024 + lane * 8;
  const int fr = lane & 15, fk = (lane >> 4) << 3;

  f32x4 acc[4][4];
  #pragma unroll
  for (int a = 0; a < 4; ++a)
    #pragma unroll
    for (int b = 0; b < 4; ++b) acc[a][b] = (f32x4){0.f, 0.f, 0.f, 0.f};

  #pragma unroll 1
  for (int seg = 0; seg < 3; ++seg) {
    const unsigned short* Ab = (seg == 2) ? Alo : Ahi;
    const unsigned short* Bb = (seg == 1) ? Blo : Bhi;
    #pragma unroll 1
    for (int kt = 0; kt < 512; kt += 32) {
      gload16(Ab + (size_t)(m0 + srow) * 512 + kt + sk, &As[ldse]);
      gload16(Ab + (size_t)(m0 + srow + 16) * 512 + kt + sk, &As[ldse + 512]);
      gload16(Bb + (size_t)(n0 + srow) * 512 + kt + sk, &Bs[ldse]);
      gload16(Bb + (size_t)(n0 + srow + 16) * 512 + kt + sk, &Bs[ldse + 512]);
      __syncthreads();
      bf16x8 af[4], bf[4];
      #pragma unroll
      for (int mf = 0; mf < 4; ++mf)
        af[mf] = *(const bf16x8*)&As[(wr * 64 + mf * 16 + fr) * 32 + fk];
      #pragma unroll
      for (int nf = 0; nf < 4; ++nf)
        bf[nf] = *(const bf16x8*)&Bs[(wc * 64 + nf * 16 + fr) * 32 + fk];
      #pragma unroll
      for (int mf = 0; mf < 4; ++mf)
        #pragma unroll
        for (int nf = 0; nf < 4; ++nf)
          acc[mf][nf] = __builtin_amdgcn_mfma_f32_16x16x32_bf16(af[mf], bf[nf],
                                                                acc[mf][nf], 0, 0, 0);
      __syncthreads();
    }
  }

  const int rgrp = (lane >> 4) << 2;
  #pragma unroll
  for (int nf = 0; nf < 4; ++nf) {
    int n = n0 + wc * 64 + nf * 16 + fr;
    float bn = bias[n];
    #pragma unroll
    for (int mf = 0; mf < 4; ++mf) {
      #pragma unroll
      for (int r = 0; r < 4; ++r) {
        int m = m0 + wr * 64 + mf * 16 + rgrp + r;
        C[(size_t)m * 32000 + n] = acc[mf][nf][r] + bn;
      }
    }
  }
}

// ---------------- single-flag sync (256 block flags, wave0 polls) ----------------
__device__ __forceinline__ void pollwait(const int* arr, int target) {
  const int tid = threadIdx.x;
  if (tid < 64) {
    const int* p0 = &arr[tid * BARSTRIDE];
    const int* p1 = &arr[(tid + 64) * BARSTRIDE];
    const int* p2 = &arr[(tid + 128) * BARSTRIDE];
    const int* p3 = &arr[(tid + 192) * BARSTRIDE];
    for (;;) {
      int a = __hip_atomic_load(p0, __ATOMIC_RELAXED, __HIP_MEMORY_SCOPE_AGENT);
      int b = __hip_atomic_load(p1, __ATOMIC_RELAXED, __HIP_MEMORY_SCOPE_AGENT);
      int c = __hip_atomic_load(p2, __ATOMIC_RELAXED, __HIP_MEMORY_SCOPE_AGENT);
      int d = __hip_atomic_load(p3, __ATOMIC_RELAXED, __HIP_MEMORY_SCOPE_AGENT);
      if (__all(min(min(a, b), min(c, d)) >= target)) break;
      __builtin_amdgcn_s_sleep(1);
    }
  }
  __syncthreads();
}

// ---------------- persistent LSTM: ONE exchange per super-step ----------------
// Super-step u: L0(t=u) + L1(t=u-1); ALL inputs (h0(u-1), h1(u-2)) come from
// super-step u-1 -> single pollwait(flag,u), single publish(flag=u+1).
// Block-cooperative (coalesced h I/O, LDS reduce); L0/L1 pointwise in waves 0/1.
__global__ __launch_bounds__(256, 1)
void lstm_seq_k(const float* __restrict__ w0p,  // packed Whh0  [256][4096]
                const float* __restrict__ w1ap, // packed Wih1
                const float* __restrict__ w1bp, // packed Whh1
                const float* __restrict__ x0pre,// [B*SEQ][2048] input gates (+biases)
                const float* __restrict__ bias1,// [2048] bih1+bhh1
                float* __restrict__ h0steps, float* __restrict__ h1steps,
                const float* __restrict__ h0init, const float* __restrict__ h1init,
                const float* __restrict__ c0init, const float* __restrict__ c1init,
                float* __restrict__ c0fin, float* __restrict__ c1fin,
                float* __restrict__ dec_out,    // [B][SEQ][Hd] or nullptr
                int* __restrict__ flag)
{
  __shared__ float w0s[4096], w1as[4096], w1bs[4096];
  __shared__ float rbuf[16384];   // [0:8192)=L0, [8192:16384)=L1
  __shared__ float gbuf[512];     // [0:256)=L0 gates, [256:512)=L1 gates

  const int blk = blockIdx.x, tid = threadIdx.x;
  const int bg = tid & 7, ks = tid >> 3;
  const int n0 = blk << 1;

  // stage all three packed weight panels once
  for (int i = tid * 4; i < 4096; i += 1024) {
    *(float4*)&w0s[i]  = *(const float4*)&w0p[((size_t)blk << 12) + i];
    *(float4*)&w1as[i] = *(const float4*)&w1ap[((size_t)blk << 12) + i];
    *(float4*)&w1bs[i] = *(const float4*)&w1bp[((size_t)blk << 12) + i];
  }

  // loop-invariant per-thread state
  const int half = (tid >> 6) & 1;               // wave0 -> L0 pointwise, wave1 -> L1
  const int pr = tid & 63;
  const int cc_ = pr & 1, b2_ = pr >> 1, nn_ = n0 + cc_;
  float creg = 0.f;
  if (tid < 128) creg = (half ? c1init : c0init)[b2_ * Hd + nn_];
  const int rcol = tid & 7, rb = tid >> 3, rbgr = rb >> 2, rbi = rb & 3;
  const int rj = ((rcol >> 1) << 9) + n0 + (rcol & 1);
  const float bv = bias1[rj];
  const float* xbase = x0pre + (size_t)rb * SEQ * G4H + rj;
  __syncthreads();

  #pragma unroll 1
  for (int u = 0; u <= SEQ; ++u) {
    const bool doL0 = (u < SEQ), doL1 = (u >= 1);
    const int wbase = ks << 3;

    // x prefetch before the wait (static address; latency hides under poll)
    float xv = doL0 ? xbase[(size_t)u * G4H] : 0.f;

    if (u > 0) pollwait(flag, u);   // all of super-step u-1's outputs visible

    // ---- h loads (coalesced float4, fresh per-step addresses) ----
    float hA[4][16];
    {
      const float* h0p = (u == 0) ? h0init : h0steps + (size_t)(u - 1) * BH;
      #pragma unroll
      for (int bi = 0; bi < 4; ++bi) {
        int b = (bg << 2) + bi;
        #pragma unroll
        for (int q = 0; q < 4; ++q) {
          float4 t = *(const float4*)&h0p[b * Hd + (ks << 4) + (q << 2)];
          hA[bi][q * 4 + 0] = t.x; hA[bi][q * 4 + 1] = t.y;
          hA[bi][q * 4 + 2] = t.z; hA[bi][q * 4 + 3] = t.w;
        }
      }
    }
    float hB[4][16];
    if (doL1) {
      const float* h1p = (u == 1) ? h1init : h1steps + (size_t)(u - 2) * BH;
      #pragma unroll
      for (int bi = 0; bi < 4; ++bi) {
        int b = (bg << 2) + bi;
        #pragma unroll
        for (int q = 0; q < 4; ++q) {
          float4 t = *(const float4*)&h1p[b * Hd + (ks << 4) + (q << 2)];
          hB[bi][q * 4 + 0] = t.x; hB[bi][q * 4 + 1] = t.y;
          hB[bi][q * 4 + 2] = t.z; hB[bi][q * 4 + 3] = t.w;
        }
      }
    }

    __attribute__((aligned(16))) float acc0[8][4];
    __attribute__((aligned(16))) float acc1[8][4];
    #pragma unroll
    for (int jj = 0; jj < 8; ++jj)
      #pragma unroll
      for (int bi = 0; bi < 4; ++bi) { acc0[jj][bi] = 0.f; acc1[jj][bi] = 0.f; }

    if (doL0) {
      #pragma unroll
      for (int kk = 0; kk < 16; ++kk) {          // Whh0 . hA
        float4 wlo = *(const float4*)&w0s[(kk << 8) + wbase];
        float4 whi = *(const float4*)&w0s[(kk << 8) + wbase + 4];
        const float* wl = (const float*)&wlo;
        const float* wh = (const float*)&whi;
        #pragma unroll
        for (int jj = 0; jj < 4; ++jj)
          #pragma unroll
          for (int bi = 0; bi < 4; ++bi) {
            acc0[jj][bi]     += wl[jj] * hA[bi][kk];
            acc0[4 + jj][bi] += wh[jj] * hA[bi][kk];
          }
      }
    }
    if (doL1) {
      #pragma unroll
      for (int kk = 0; kk < 16; ++kk) {          // Wih1 . hA
        float4 wlo = *(const float4*)&w1as[(kk << 8) + wbase];
        float4 whi = *(const float4*)&w1as[(kk << 8) + wbase + 4];
        const float* wl = (const float*)&wlo;
        const float* wh = (const float*)&whi;
        #pragma unroll
        for (int jj = 0; jj < 4; ++jj)
          #pragma unroll
          for (int bi = 0; bi < 4; ++bi) {
            acc1[jj][bi]     += wl[jj] * hA[bi][kk];
            acc1[4 + jj][bi] += wh[jj] * hA[bi][kk];
          }
      }
      #pragma unroll
      for (int kk = 0; kk < 16; ++kk) {          // Whh1 . hB
        float4 wlo = *(const float4*)&w1bs[(kk << 8) + wbase];
        float4 whi = *(const float4*)&w1bs[(kk << 8) + wbase + 4];
        const float* wl = (const float*)&wlo;
        const float* wh = (const float*)&whi;
        #pragma unroll
        for (int jj = 0; jj < 4; ++jj)
          #pragma unroll
          for (int bi = 0; bi < 4; ++bi) {
            acc1[jj][bi]     += wl[jj] * hB[bi][kk];
            acc1[4 + jj][bi] += wh[jj] * hB[bi][kk];
          }
      }
    }

    // ---- both reductions through doubled rbuf, one barrier pair ----
    if (doL0) {
      #pragma unroll
      for (int jj = 0; jj < 8; ++jj)
        *(float4*)&rbuf[(ks << 8) + (bg << 5) + ((jj ^ bg) << 2)] = *(const float4*)acc0[jj];
    }
    if (doL1) {
      #pragma unroll
      for (int jj = 0; jj < 8; ++jj)
        *(float4*)&rbuf[8192 + (ks << 8) + (bg << 5) + ((jj ^ bg) << 2)] = *(const float4*)acc1[jj];
    }
    __syncthreads();
    if (doL0) {
      float s = xv;
      #pragma unroll 8
      for (int k2 = 0; k2 < 32; ++k2)
        s += rbuf[(k2 << 8) + (rbgr << 5) + ((rcol ^ rbgr) << 2) + rbi];
      gbuf[(rcol << 5) + rb] = s;
    }
    if (doL1) {
      float s = bv;
      #pragma unroll 8
      for (int k2 = 0; k2 < 32; ++k2)
        s += rbuf[8192 + (k2 << 8) + (rbgr << 5) + ((rcol ^ rbgr) << 2) + rbi];
      gbuf[256 + (rcol << 5) + rb] = s;
    }
    __syncthreads();

    // ---- pointwise: wave0 -> L0, wave1 -> L1 (parallel, coalesced stores) ----
    if (tid < 64 && doL0) {
      float gi = gbuf[((0 + cc_) << 5) + b2_];
      float gf = gbuf[((2 + cc_) << 5) + b2_];
      float gg = gbuf[((4 + cc_) << 5) + b2_];
      float go = gbuf[((6 + cc_) << 5) + b2_];
      float i_ = 1.f / (1.f + expf(-gi));
      float f_ = 1.f / (1.f + expf(-gf));
      float o_ = 1.f / (1.f + expf(-go));
      float g_ = tanhf(gg);
      float cn = f_ * creg + i_ * g_;
      float hn = o_ * tanhf(cn);
      creg = cn;
      __hip_atomic_store(&h0steps[(size_t)u * BH + b2_ * Hd + nn_], hn,
                         __ATOMIC_RELAXED, __HIP_MEMORY_SCOPE_AGENT);
    } else if (tid >= 64 && tid < 128 && doL1) {
      const int t = u - 1;
      float gi = gbuf[256 + ((0 + cc_) << 5) + b2_];
      float gf = gbuf[256 + ((2 + cc_) << 5) + b2_];
      float gg = gbuf[256 + ((4 + cc_) << 5) + b2_];
      float go = gbuf[256 + ((6 + cc_) << 5) + b2_];
      float i_ = 1.f / (1.f + expf(-gi));
      float f_ = 1.f / (1.f + expf(-gf));
      float o_ = 1.f / (1.f + expf(-go));
      float g_ = tanhf(gg);
      float cn = f_ * creg + i_ * g_;
      float hn = o_ * tanhf(cn);
      creg = cn;
      __hip_atomic_store(&h1steps[(size_t)t * BH + b2_ * Hd + nn_], hn,
                         __ATOMIC_RELAXED, __HIP_MEMORY_SCOPE_AGENT);
      if (dec_out) dec_out[((size_t)b2_ * SEQ + t) * Hd + nn_] = hn;
    }

    // drain every wave's write-through stores, then single publish
    asm volatile("s_waitcnt vmcnt(0)" ::: "memory");
    __syncthreads();
    if (tid == 0)
      __hip_atomic_store(&flag[blk * BARSTRIDE], u + 1,
                         __ATOMIC_RELAXED, __HIP_MEMORY_SCOPE_AGENT);
  }

  // final c handoff
  if (tid < 128) {
    float* cf = half ? c1fin : c0fin;
    cf[b2_ * Hd + nn_] = creg;
  }
}

// ---------------- host ----------------
extern "C" void kernel_launch(void* const* d_in, const int* in_sizes, int n_in,
                              void* d_out, int out_size, void* d_ws, size_t ws_size,
                              hipStream_t stream) {
  const int*   src  = (const int*)d_in[0];
  const int*   tgt  = (const int*)d_in[1];
  const float* emb  = (const float*)d_in[2];
  const float* Wout = (const float*)d_in[3];
  const float* bout = (const float*)d_in[4];
  const float* eWih0 = (const float*)d_in[5];
  const float* eWhh0 = (const float*)d_in[6];
  const float* ebih0 = (const float*)d_in[7];
  const float* ebhh0 = (const float*)d_in[8];
  const float* eWih1 = (const float*)d_in[9];
  const float* eWhh1 = (const float*)d_in[10];
  const float* ebih1 = (const float*)d_in[11];
  const float* ebhh1 = (const float*)d_in[12];
  const float* dWih0 = (const float*)d_in[13];
  const float* dWhh0 = (const float*)d_in[14];
  const float* dbih0 = (const float*)d_in[15];
  const float* dbhh0 = (const float*)d_in[16];
  const float* dWih1 = (const float*)d_in[17];
  const float* dWhh1 = (const float*)d_in[18];
  const float* dbih1 = (const float*)d_in[19];
  const float* dbhh1 = (const float*)d_in[20];

  float* ws = (float*)d_ws;
  char*  wsb = (char*)d_ws;
  // float offsets
  const size_t OFF_EMB  = 0;          // dead after input gemms
  const size_t OFF_X0   = 1048576;
  const size_t OFF_W0E  = 9437184;
  const size_t OFF_W1AE = 10485760;
  const size_t OFF_W1BE = 11534336;
  const size_t OFF_W0D  = 12582912;
  const size_t OFF_W1AD = 13631488;
  const size_t OFF_W1BD = 14680064;
  const size_t OFF_BS0E = 15728640;
  const size_t OFF_B1E  = 15730688;
  const size_t OFF_BS0D = 15732736;
  const size_t OFF_B1D  = 15734784;
  const size_t OFF_H0   = 15736832;   // 128*BH (per-step h0 slots)
  const size_t OFF_H1   = 17833984;   // 128*BH
  const size_t OFF_C0   = 19931136;   // BH (enc-final c0 -> dec init)
  const size_t OFF_C1   = 19947520;   // BH
  const size_t OFF_Z    = 19963904;   // BH zeros
  const size_t OFF_BAR  = 19980288;   // 2 x 8192 ints (enc flag, dec flag)
  const size_t OFF_DOUT = 20013056;   // 2,097,152 f -> byte end 88,440,832
  unsigned short* Ahi = (unsigned short*)(wsb + 88440832);   // 4096*512
  unsigned short* Alo = (unsigned short*)(wsb + 92635136);   // 4096*512
  unsigned short* Bhi = (unsigned short*)(wsb + 0);          // 32000*512 (dead low region)
  unsigned short* Blo = (unsigned short*)(wsb + 32768000);
  const bool use_mfma = ws_size >= 96829440ull;

  int* eflag = (int*)(ws + OFF_BAR);
  int* dflag = eflag + 8192;

  // pack weights + bias sums
  pack_w_k<<<256, 256, 0, stream>>>(eWhh0, ws + OFF_W0E);
  pack_w_k<<<256, 256, 0, stream>>>(eWih1, ws + OFF_W1AE);
  pack_w_k<<<256, 256, 0, stream>>>(eWhh1, ws + OFF_W1BE);
  pack_w_k<<<256, 256, 0, stream>>>(dWhh0, ws + OFF_W0D);
  pack_w_k<<<256, 256, 0, stream>>>(dWih1, ws + OFF_W1AD);
  pack_w_k<<<256, 256, 0, stream>>>(dWhh1, ws + OFF_W1BD);
  bias_sum_k<<<8, 256, 0, stream>>>(ebih0, ebhh0, ws + OFF_BS0E);
  bias_sum_k<<<8, 256, 0, stream>>>(ebih1, ebhh1, ws + OFF_B1E);
  bias_sum_k<<<8, 256, 0, stream>>>(dbih0, dbhh0, ws + OFF_BS0D);
  bias_sum_k<<<8, 256, 0, stream>>>(dbih1, dbhh1, ws + OFF_B1D);

  // zero zbuf + flag arrays every call (graph replay safe)
  hipMemsetAsync(ws + OFF_Z, 0, (size_t)(BH + 16384) * 4, stream);

  // encoder
  embed_k<<<1024, 256, 0, stream>>>(src, emb, ws + OFF_EMB);
  gemm_nt_k<<<dim3(32, 64), 256, 0, stream>>>(ws + OFF_EMB, eWih0, ws + OFF_BS0E,
                                              ws + OFF_X0, 256, 2048);
  lstm_seq_k<<<256, 256, 0, stream>>>(ws + OFF_W0E, ws + OFF_W1AE, ws + OFF_W1BE,
                                      ws + OFF_X0, ws + OFF_B1E,
                                      ws + OFF_H0, ws + OFF_H1,
                                      ws + OFF_Z, ws + OFF_Z,      // h inits (zeros)
                                      ws + OFF_Z, ws + OFF_Z,      // c inits (zeros)
                                      ws + OFF_C0, ws + OFF_C1,    // c finals
                                      nullptr, eflag);

  // decoder (inits = encoder finals)
  embed_k<<<1024, 256, 0, stream>>>(tgt, emb, ws + OFF_EMB);
  gemm_nt_k<<<dim3(32, 64), 256, 0, stream>>>(ws + OFF_EMB, dWih0, ws + OFF_BS0D,
                                              ws + OFF_X0, 256, 2048);
  lstm_seq_k<<<256, 256, 0, stream>>>(ws + OFF_W0D, ws + OFF_W1AD, ws + OFF_W1BD,
                                      ws + OFF_X0, ws + OFF_B1D,
                                      ws + OFF_H0, ws + OFF_H1,
                                      ws + OFF_H0 + (size_t)127 * BH,
                                      ws + OFF_H1 + (size_t)127 * BH,
                                      ws + OFF_C0, ws + OFF_C1,
                                      ws + OFF_C0, ws + OFF_C1,
                                      ws + OFF_DOUT, dflag);

  // vocab projection
  if (use_mfma) {
    split_k<<<2048, 256, 0, stream>>>(ws + OFF_DOUT, Ahi, Alo);
    split_k<<<16000, 256, 0, stream>>>(Wout, Bhi, Blo);   // overlays dead low region
    gemm_bf16_split_k<<<dim3(32, 250), 256, 0, stream>>>(Ahi, Alo, Bhi, Blo,
                                                         bout, (float*)d_out);
  } else {
    gemm_nt_k<<<dim3(500, 64), 256, 0, stream>>>(ws + OFF_DOUT, Wout, bout,
                                                 (float*)d_out, 512, 32000);
  }
}